// Round 9
// baseline (271.847 us; speedup 1.0000x reference)
//
#include <hip/hip_runtime.h>

// Problem constants: B=2, S=2048, D=1024, H=16, Hd=64
#define S_   2048
#define D_   1024

typedef __attribute__((ext_vector_type(8))) __bf16 bf16x8;
typedef __attribute__((ext_vector_type(4))) __bf16 bf16x4;
typedef __attribute__((ext_vector_type(4))) float f32x4;
typedef __attribute__((ext_vector_type(4))) float float4v;
typedef __attribute__((ext_vector_type(2))) unsigned int u32x2;
typedef __attribute__((ext_vector_type(4))) unsigned int u32x4;

// Workspace layout (in bf16/short elements)
#define XQ_OFF   0           // 4096x1024 bf16 inputs
#define XK_OFF   4194304
#define XV_OFF   8388608
#define WQT_OFF  12582912    // W^T 1024x1024 bf16, [n][k]
#define WKT_OFF  13631488
#define WVT_OFF  14680064
#define WOT_OFF  15728640
#define QH_OFF   16777216    // (B,H,S,Hd) bf16, PRE-SCALED by log2e/8
#define KH_OFF   20971520    // (B,H,S,Hd) bf16
#define VHT_OFF  25165824    // (B,H)(sblk 16)(hd 64)(s 128) bf16 blocked V^T
#define CTX_OFF  29360128    // (B,S,D) bf16
#define WS_BYTES 67108864ULL

#if __has_builtin(__builtin_amdgcn_exp2f)
#define EXP2(x) __builtin_amdgcn_exp2f(x)
#else
#define EXP2(x) __expf((x) * 0.69314718056f)
#endif
#define QSCALE 0.1803368801f  // 0.125 * log2(e)

__device__ __forceinline__ unsigned short f2b(float f) {  // fp32->bf16 RNE
  unsigned u = __builtin_bit_cast(unsigned, f);
  u += 0x7fffu + ((u >> 16) & 1u);
  return (unsigned short)(u >> 16);
}
__device__ __forceinline__ float b2f(unsigned s) {
  return __builtin_bit_cast(float, s << 16);
}

// ------------- K0: merged fp32->bf16 convert (x: qkv) + weight transpose ----
__global__ __launch_bounds__(256) void cvt_all(const float* __restrict__ q,
    const float* __restrict__ k, const float* __restrict__ v,
    const float* __restrict__ wq, const float* __restrict__ wk,
    const float* __restrict__ wv, const float* __restrict__ wo,
    short* __restrict__ ws) {
  __shared__ float tile[32][33];
  int b = blockIdx.x, tid = threadIdx.x;
  if (b < 12288) {
    int y = b >> 12, x = b & 4095;
    const float* src = (y == 0) ? q : (y == 1) ? k : v;
    short* dst = ws + (size_t)y * 4194304;
    size_t t = (size_t)x * 256 + tid;
    float4v f = *(const float4v*)(src + t * 4);
    u32x2 p;
    p[0] = (unsigned)f2b(f[0]) | ((unsigned)f2b(f[1]) << 16);
    p[1] = (unsigned)f2b(f[2]) | ((unsigned)f2b(f[3]) << 16);
    *(u32x2*)(dst + t * 4) = p;
    return;
  }
  int b2 = b - 12288;            // weight transpose: 4096 blocks
  int z = b2 >> 10, rem = b2 & 1023;
  int by = rem >> 5, bx = rem & 31;
  const float* W = (z == 0) ? wq : (z == 1) ? wk : (z == 2) ? wv : wo;
  short* Wt = ws + WQT_OFF + (size_t)z * 1048576;
  int tx = tid & 31, ty = tid >> 5;  // 32 x 8
#pragma unroll
  for (int i = 0; i < 4; ++i)
    tile[ty + i * 8][tx] =
        W[(size_t)(by * 32 + ty + i * 8) * D_ + bx * 32 + tx];
  __syncthreads();
#pragma unroll
  for (int i = 0; i < 4; ++i)
    Wt[(size_t)(bx * 32 + ty + i * 8) * D_ + by * 32 + tx] =
        (short)f2b(tile[tx][ty + i * 8]);
}

// ---------------- K1/K3: bf16 GEMM, 128x128 tile, 2-phase ----------------
__device__ __forceinline__ void stage_tile(const short* __restrict__ g,
                                           short* l, int w, int lane) {
  int lrow = lane >> 3, lcol = (lane & 7) * 8;
#pragma unroll
  for (int c = 0; c < 4; ++c) {
    int seg = c * 4 + w;  // 0..15, 8 rows each
    const short* gp = g + (size_t)(seg * 8 + lrow) * 1024 + lcol;
    short* lp = l + seg * 512 + lane * 8;
    __builtin_amdgcn_global_load_lds(
        (const __attribute__((address_space(1))) void*)gp,
        (__attribute__((address_space(3))) void*)lp, 16, 0, 0);
  }
}

__global__ __launch_bounds__(256) void gemm_bf16(short* __restrict__ ws,
    const float* __restrict__ bq, const float* __restrict__ bk,
    const float* __restrict__ bv, const float* __restrict__ bo,
    float* __restrict__ out, int mode_base) {
  const int tid = threadIdx.x, lane = tid & 63, w = tid >> 6;
  const int wm = w >> 1, wn = w & 1;
  const int ln15 = lane & 15, g = lane >> 4;
  const int bm = blockIdx.y, bn = blockIdx.x;
  const int mode = (mode_base == 3) ? 3 : (int)blockIdx.z;

  const short* A; const short* Bt; const float* bias;
  if (mode == 0)      { A = ws + XQ_OFF;  Bt = ws + WQT_OFF; bias = bq; }
  else if (mode == 1) { A = ws + XK_OFF;  Bt = ws + WKT_OFF; bias = bk; }
  else if (mode == 2) { A = ws + XV_OFF;  Bt = ws + WVT_OFF; bias = bv; }
  else                { A = ws + CTX_OFF; Bt = ws + WOT_OFF; bias = bo; }

  __shared__ short smem[2][2][8192];   // [A/B][dbuf][128*64]
  short (*sA)[8192] = smem[0];
  short (*sB)[8192] = smem[1];

  f32x4 acc[4][4] = {};

  const short* Ab = A + (size_t)bm * 128 * 1024;
  const short* Bb = Bt + (size_t)bn * 128 * 1024;

  stage_tile(Ab, sA[0], w, lane);
  stage_tile(Bb, sB[0], w, lane);
  __syncthreads();

  int cur = 0;
#pragma unroll 1
  for (int kt = 0; kt < 16; ++kt) {
    if (kt < 15) {
      stage_tile(Ab + (kt + 1) * 64, sA[cur ^ 1], w, lane);
      stage_tile(Bb + (kt + 1) * 64, sB[cur ^ 1], w, lane);
    }
#pragma unroll
    for (int kk = 0; kk < 2; ++kk) {
      bf16x8 af[4], bfr[4];
#pragma unroll
      for (int m = 0; m < 4; ++m)
        af[m] = *(const bf16x8*)&sA[cur][(wm * 64 + m * 16 + ln15) * 64 + kk * 32 + g * 8];
#pragma unroll
      for (int n = 0; n < 4; ++n)
        bfr[n] = *(const bf16x8*)&sB[cur][(wn * 64 + n * 16 + ln15) * 64 + kk * 32 + g * 8];
#pragma unroll
      for (int m = 0; m < 4; ++m)
#pragma unroll
        for (int n = 0; n < 4; ++n)
          acc[m][n] = __builtin_amdgcn_mfma_f32_16x16x32_bf16(af[m], bfr[n], acc[m][n], 0, 0, 0);
    }
    __syncthreads();
    cur ^= 1;
  }

  float bb[4];
#pragma unroll
  for (int n = 0; n < 4; ++n) bb[n] = bias[bn * 128 + wn * 64 + n * 16 + ln15];

  if (mode == 3) {
#pragma unroll
    for (int m = 0; m < 4; ++m) {
      int row0 = bm * 128 + wm * 64 + m * 16 + g * 4;
#pragma unroll
      for (int n = 0; n < 4; ++n) {
        int col = bn * 128 + wn * 64 + n * 16 + ln15;
#pragma unroll
        for (int r = 0; r < 4; ++r)
          out[(size_t)(row0 + r) * 1024 + col] = acc[m][n][r] + bb[n];
      }
    }
    return;
  }

  float sc = (mode == 0) ? QSCALE : 1.0f;
  short (*tile)[136] = (short(*)[136])smem;  // 128x136 bf16
#pragma unroll
  for (int m = 0; m < 4; ++m)
#pragma unroll
    for (int n = 0; n < 4; ++n)
#pragma unroll
      for (int r = 0; r < 4; ++r)
        tile[wm * 64 + m * 16 + g * 4 + r][wn * 64 + n * 16 + ln15] =
            (short)f2b((acc[m][n][r] + bb[n]) * sc);
  __syncthreads();

  if (mode == 2) {
    // blocked vht: [bh][sblk(16)][hd(64)][s(128)]
    int dcol = tid >> 1, sh = (tid & 1) * 64;
    int colg = bn * 128 + dcol, h = colg >> 6, hd = colg & 63;
    int b = bm >> 4, sblk = bm & 15;
    short* dst = ws + VHT_OFF +
                 ((size_t)((b * 16 + h) * 16 + sblk)) * 8192 + hd * 128 + sh;
#pragma unroll
    for (int j = 0; j < 8; ++j) {
      u32x4 pk;
#pragma unroll
      for (int q = 0; q < 4; ++q) {
        unsigned lo = (unsigned short)tile[sh + j * 8 + q * 2][dcol];
        unsigned hi = (unsigned short)tile[sh + j * 8 + q * 2 + 1][dcol];
        pk[q] = lo | (hi << 16);
      }
      *(u32x4*)(dst + j * 8) = pk;
    }
  } else {
    int r = tid >> 1, sh = (tid & 1) * 64;
    int colg = bn * 128 + sh, h = colg >> 6;
    int sg = bm * 128 + r, b = sg >> 11, sl = sg & 2047;
    short* dst = ws + ((mode == 0) ? QH_OFF : KH_OFF) +
                 (((size_t)(b * 16 + h)) * 2048 + sl) * 64;
#pragma unroll
    for (int j = 0; j < 8; ++j)
      *(u32x4*)(dst + j * 8) = *(const u32x4*)&tile[r][sh + j * 8];
  }
}

// ---------------- K2: fused attention (r8 staging + r9 pipeline) ----------
// r8 proved block-level global_load_lds staging is the fix for the TA path.
// r9: (a) pass 1 uses 128-k tiles (16 iters, half the barriers);
//     (b) pass 2 runs a 2-deep P pipeline: QK^T(i+1)->PlWr overlaps
//         PV(i)+stores(i)<-PlRd. PlA/PlB are distinct __shared__ objects so
//         the scheduler interleaves the independent chains (no per-iter
//         lgkm fences -- Pl rows are wave-private).
// Staging: K 2-ahead, V 1-ahead; per-iter vmcnt(16) drains only the staging
// loads (older) and leaves the 16 attn stores in flight across the barrier.
__global__ __launch_bounds__(512) void attn_k(short* __restrict__ ws,
                                              float* __restrict__ attn) {
  const int tid = threadIdx.x, lane = tid & 63, w = tid >> 6;  // 8 waves
  const int ln15 = lane & 15, g = lane >> 4, ln7 = lane & 7;
  // XCD-affine swizzle: same-bh blocks land on the same XCD
  int bid = blockIdx.x;                  // 512 blocks
  int qt = (bid >> 3) & 15;              // 16 q-tiles of 128 rows
  int bh = (bid & 7) + 8 * (bid >> 7);   // 4 bh per XCD
  const int q0 = qt * 128;

  const short* Q  = ws + QH_OFF  + ((size_t)bh * 2048 + q0) * 64;
  const short* K  = ws + KH_OFF  + (size_t)bh * 2048 * 64;
  const short* Vt = ws + VHT_OFF + (size_t)bh * 131072;

  __shared__ short sKV[4][4096];   // pass1: 2x16KB K dbuf; pass2: K[0..1],V[2..3]
  __shared__ short PlA[128][72];   // P bf16 ping
  __shared__ short PlB[128][72];   // P bf16 pong

  // staging decomposition: 512 threads x 16B = 8KB per call.
  // LDS[row][c] = G[row][c ^ (row&7)]  (16B chunks; involution)
  const int srow = tid >> 3, sc = tid & 7;
  const int scsw = sc ^ (srow & 7);
  const int sdst = tid * 8;  // short offset

#define STAGE1(t1, b)                                                         \
  do {                                                                        \
    __builtin_amdgcn_global_load_lds(                                         \
        (const __attribute__((address_space(1))) void*)(K + ((t1) * 128 + srow) * 64 + scsw * 8),      \
        (__attribute__((address_space(3))) void*)(&sKV[2 * (b)][sdst]), 16, 0, 0);                     \
    __builtin_amdgcn_global_load_lds(                                         \
        (const __attribute__((address_space(1))) void*)(K + ((t1) * 128 + 64 + srow) * 64 + scsw * 8), \
        (__attribute__((address_space(3))) void*)(&sKV[2 * (b) + 1][sdst]), 16, 0, 0);                 \
  } while (0)
#define STAGE_K2(kt)                                                          \
  __builtin_amdgcn_global_load_lds(                                           \
      (const __attribute__((address_space(1))) void*)(K + ((kt) * 64 + srow) * 64 + scsw * 8),         \
      (__attribute__((address_space(3))) void*)(&sKV[(kt) & 1][sdst]), 16, 0, 0)
#define STAGE_V2(kt)                                                          \
  __builtin_amdgcn_global_load_lds(                                           \
      (const __attribute__((address_space(1))) void*)(Vt + ((kt) >> 1) * 8192 + srow * 128 + ((kt) & 1) * 64 + scsw * 8), \
      (__attribute__((address_space(3))) void*)(&sKV[2 + ((kt) & 1)][sdst]), 16, 0, 0)

  // Q fragments: wave w owns q rows [w*16, w*16+16)
  bf16x8 qf0 = *(const bf16x8*)&Q[(w * 16 + ln15) * 64 + g * 8];
  bf16x8 qf1 = *(const bf16x8*)&Q[(w * 16 + ln15) * 64 + 32 + g * 8];

  // ---- pass 1: softmax denominators, 128-k tiles ----
  STAGE1(0, 0);
  asm volatile("s_waitcnt vmcnt(0)" ::: "memory");
  __builtin_amdgcn_s_barrier();

  float ps0 = 0.f, ps1 = 0.f;
#pragma unroll 1
  for (int t = 0; t < 16; ++t) {
    int b = t & 1;
    if (t < 15) STAGE1(t + 1, b ^ 1);
#pragma unroll
    for (int m = 0; m < 8; ++m) {
      const short* kbase = &sKV[2 * b + (m >> 2)][((m * 16 + ln15) & 63) * 64];
      bf16x8 ka0 = *(const bf16x8*)&kbase[(g ^ ln7) * 8];
      bf16x8 ka1 = *(const bf16x8*)&kbase[((4 + g) ^ ln7) * 8];
      f32x4 c = {0.f, 0.f, 0.f, 0.f};
      c = __builtin_amdgcn_mfma_f32_16x16x32_bf16(ka0, qf0, c, 0, 0, 0);
      c = __builtin_amdgcn_mfma_f32_16x16x32_bf16(ka1, qf1, c, 0, 0, 0);
      ps0 += EXP2(c[0]) + EXP2(c[1]);
      ps1 += EXP2(c[2]) + EXP2(c[3]);
    }
    asm volatile("s_waitcnt vmcnt(0)" ::: "memory");
    __builtin_amdgcn_s_barrier();
  }
  float ps = ps0 + ps1;
  ps += __shfl_xor(ps, 16, 64);  // reduce the 4 k-groups (same q col)
  ps += __shfl_xor(ps, 32, 64);
  float ri = 1.0f / ps;

  // ---- pass 2: 2-deep pipeline ----
#define QKT_BODY(kti, PLW)                                                    \
  do {                                                                        \
    _Pragma("unroll") for (int m = 0; m < 4; ++m) {                           \
      const short* kbase = &sKV[(kti) & 1][(m * 16 + ln15) * 64];             \
      bf16x8 ka0 = *(const bf16x8*)&kbase[(g ^ ln7) * 8];                     \
      bf16x8 ka1 = *(const bf16x8*)&kbase[((4 + g) ^ ln7) * 8];               \
      f32x4 c = {0.f, 0.f, 0.f, 0.f};                                         \
      c = __builtin_amdgcn_mfma_f32_16x16x32_bf16(ka0, qf0, c, 0, 0, 0);      \
      c = __builtin_amdgcn_mfma_f32_16x16x32_bf16(ka1, qf1, c, 0, 0, 0);      \
      bf16x4 pb;                                                              \
      pb[0] = (__bf16)(EXP2(c[0]) * ri);                                      \
      pb[1] = (__bf16)(EXP2(c[1]) * ri);                                      \
      pb[2] = (__bf16)(EXP2(c[2]) * ri);                                      \
      pb[3] = (__bf16)(EXP2(c[3]) * ri);                                      \
      *(bf16x4*)&PLW[w * 16 + ln15][m * 16 + g * 4] = pb;                     \
    }                                                                         \
  } while (0)

#define FULL_BODY(i, PLR, PLW)                                                \
  do {                                                                        \
    if ((i) < 30) STAGE_K2((i) + 2);                                          \
    if ((i) < 31) STAGE_V2((i) + 1);                                          \
    if ((i) < 31) QKT_BODY((i) + 1, PLW);                                     \
    _Pragma("unroll") for (int kk = 0; kk < 2; ++kk) {                        \
      bf16x8 pa = *(const bf16x8*)&PLR[w * 16 + ln15][kk * 32 + g * 8];       \
      _Pragma("unroll") for (int n = 0; n < 4; ++n) {                         \
        const short* vbase = &sKV[2 + ((i) & 1)][(n * 16 + ln15) * 64];       \
        bf16x8 vb = *(const bf16x8*)&vbase[((kk * 4 + g) ^ ln7) * 8];         \
        cacc[n] = __builtin_amdgcn_mfma_f32_16x16x32_bf16(pa, vb, cacc[n], 0, 0, 0); \
      }                                                                       \
    }                                                                         \
    {                                                                         \
      float* ab = attn + ((size_t)(bh * 2048 + q0 + w * 16)) * 2048 + (i) * 64 + lane; \
      _Pragma("unroll") for (int r = 0; r < 16; ++r)                          \
        ab[(size_t)r * 2048] = b2f((unsigned short)PLR[w * 16 + r][lane]);    \
    }                                                                         \
    asm volatile("s_waitcnt vmcnt(16)" ::: "memory");                         \
    __builtin_amdgcn_s_barrier();                                             \
  } while (0)

  f32x4 cacc[4] = {};

  // prologue: stage K0,V0,K1; compute QK^T(0) -> PlA
  STAGE_K2(0);
  STAGE_V2(0);
  STAGE_K2(1);
  asm volatile("s_waitcnt vmcnt(0)" ::: "memory");
  __builtin_amdgcn_s_barrier();
  QKT_BODY(0, PlA);
  asm volatile("s_waitcnt lgkmcnt(0)" ::: "memory");  // K0 reads done by all
  __builtin_amdgcn_s_barrier();                       // before iter0 restages

#pragma unroll 1
  for (int i2 = 0; i2 < 32; i2 += 2) {
    FULL_BODY(i2, PlA, PlB);
    FULL_BODY(i2 + 1, PlB, PlA);
  }

  // ctx epilogue -> (B,S,D) bf16, repacked via PlA slice to 128B rows
  {
    short* Pw = &PlA[w * 16][0];
#pragma unroll
    for (int n = 0; n < 4; ++n)
#pragma unroll
      for (int r = 0; r < 4; ++r)
        Pw[(g * 4 + r) * 72 + n * 16 + ln15] = (short)f2b(cacc[n][r]);
    asm volatile("s_waitcnt lgkmcnt(0)" ::: "memory");
    __builtin_amdgcn_sched_barrier(0);
    int b = bh >> 4, h = bh & 15;
    int row = lane >> 3, col = (lane & 7) * 8;
#pragma unroll
    for (int i = 0; i < 2; ++i) {
      int q = q0 + w * 16 + i * 8 + row;
      u32x4 pk = *(const u32x4*)&Pw[(i * 8 + row) * 72 + col];
      *(u32x4*)&ws[CTX_OFF + ((size_t)(b * 2048 + q)) * 1024 + h * 64 + col] = pk;
    }
  }
#undef STAGE1
#undef STAGE_K2
#undef STAGE_V2
#undef QKT_BODY
#undef FULL_BODY
}

extern "C" void kernel_launch(void* const* d_in, const int* in_sizes, int n_in,
                              void* d_out, int out_size, void* d_ws, size_t ws_size,
                              hipStream_t stream) {
  const float* q  = (const float*)d_in[0];
  const float* k  = (const float*)d_in[1];
  const float* v  = (const float*)d_in[2];
  const float* wq = (const float*)d_in[3];
  const float* bq = (const float*)d_in[4];
  const float* wk = (const float*)d_in[5];
  const float* bk = (const float*)d_in[6];
  const float* wv = (const float*)d_in[7];
  const float* bv = (const float*)d_in[8];
  const float* wo = (const float*)d_in[9];
  const float* bo = (const float*)d_in[10];
  float* out  = (float*)d_out;
  float* attn = out + 4194304;  // out (2,2048,1024) then attn (2,16,2048,2048)
  short* ws = (short*)d_ws;
  if (ws_size < WS_BYTES) return;  // need 64 MB scratch

  cvt_all<<<dim3(16384), 256, 0, stream>>>(q, k, v, wq, wk, wv, wo, ws);
  gemm_bf16<<<dim3(8, 32, 3), 256, 0, stream>>>(ws, bq, bk, bv, bo, out, 0);
  attn_k<<<dim3(512), 512, 0, stream>>>(ws, attn);
  gemm_bf16<<<dim3(8, 32, 1), 256, 0, stream>>>(ws, bq, bk, bv, bo, out, 3);
}